// Round 1
// baseline (520.467 us; speedup 1.0000x reference)
//
#include <hip/hip_runtime.h>
#include <hip/hip_bf16.h>

// ExpLeak: out[b,t,n] = alpha*out[b,t-1,n] + in[b,t,n], alpha = exp(-1/tau).
// B=16, T=1024, N=4096, fp32.
//
// Strategy: block = 1024 threads = 64 n-columns x 16 T-chunks (64 t each).
// Each thread holds its chunk in registers, does a local scan, carries are
// combined across chunks via LDS (exact linear-recurrence decomposition:
// out = local_scan + alpha^(j+1) * carry_in).

constexpr int T = 1024;
constexpr int N = 4096;
constexpr int B = 16;
constexpr int CHUNKS = 16;   // T-chunks per column
constexpr int CLEN = 64;     // t per chunk
constexpr int NCOL = 64;     // n-columns per block

__global__ __launch_bounds__(1024) void expleak_kernel(
    const float* __restrict__ in, const float* __restrict__ tau_mem,
    float* __restrict__ out) {
  __shared__ float s_end[CHUNKS * NCOL];
  __shared__ float s_carry[CHUNKS * NCOL];

  const int tid = threadIdx.x;
  const int c = tid >> 6;        // chunk index 0..15 (one wave per chunk)
  const int l = tid & 63;        // n-lane 0..63 (consecutive n -> coalesced)
  const int b = blockIdx.x >> 6; // batch 0..15
  const int ng = blockIdx.x & 63; // n-group 0..63

  const float tau = tau_mem[0];
  const float alpha = expf(-1.0f / tau);
  const float aL = expf(-(float)CLEN / tau);  // alpha^CLEN exactly

  const unsigned base = ((unsigned)(b * T) + (unsigned)(c * CLEN)) * (unsigned)N
                        + (unsigned)(ng * NCOL + l);

  // Load chunk (64 coalesced wave-loads, stride N between t steps)
  float v[CLEN];
#pragma unroll
  for (int j = 0; j < CLEN; ++j) v[j] = in[base + (unsigned)j * N];

  // Local scan with zero initial state
  float s = 0.0f;
#pragma unroll
  for (int j = 0; j < CLEN; ++j) {
    s = fmaf(alpha, s, v[j]);
    v[j] = s;
  }
  s_end[c * NCOL + l] = s;
  __syncthreads();

  // Wave 0: serial carry combine across the 16 chunks (per n-lane)
  if (c == 0) {
    float S = 0.0f;
#pragma unroll
    for (int cc = 0; cc < CHUNKS; ++cc) {
      s_carry[cc * NCOL + l] = S;           // carry INTO chunk cc
      S = fmaf(aL, S, s_end[cc * NCOL + l]); // state at end of chunk cc
    }
  }
  __syncthreads();

  // Fix up with incoming carry and store: out = v[j] + alpha^(j+1)*carry
  const float carry = s_carry[c * NCOL + l];
  float f = alpha;
#pragma unroll
  for (int j = 0; j < CLEN; ++j) {
    out[base + (unsigned)j * N] = fmaf(f, carry, v[j]);
    f *= alpha;
  }
}

extern "C" void kernel_launch(void* const* d_in, const int* in_sizes, int n_in,
                              void* d_out, int out_size, void* d_ws, size_t ws_size,
                              hipStream_t stream) {
  const float* in = (const float*)d_in[0];
  const float* tau = (const float*)d_in[1];
  float* out = (float*)d_out;
  const int grid = B * (N / NCOL);  // 16 * 64 = 1024 blocks
  expleak_kernel<<<grid, CHUNKS * NCOL, 0, stream>>>(in, tau, out);
}

// Round 2
// 440.629 us; speedup vs baseline: 1.1812x; 1.1812x over previous
//
#include <hip/hip_runtime.h>
#include <hip/hip_bf16.h>

// ExpLeak: out[b,t,n] = alpha*out[b,t-1,n] + in[b,t,n], alpha = exp(-1/tau).
// B=16, T=1024, N=4096, fp32.
//
// Strategy: block = 1024 threads = 32 n-columns x 32 T-chunks (32 t each).
// Each thread holds its chunk in REGISTERS (v[32] -> no scratch spill at the
// 128-VGPR / 4-waves-per-SIMD budget; R1's v[64] spilled and doubled HBM
// writes). Local scan in registers; chunk carries combined across the 32
// chunks via LDS (exact linear-recurrence decomposition:
// out = local_scan + alpha^(j+1) * carry_in).

constexpr int T = 1024;
constexpr int N = 4096;
constexpr int B = 16;
constexpr int CHUNKS = 32;   // T-chunks per column
constexpr int CLEN = 32;     // t per chunk  (fits in VGPRs, unlike 64)
constexpr int NCOL = 32;     // n-columns per block

__global__ __launch_bounds__(1024, 4) void expleak_kernel(
    const float* __restrict__ in, const float* __restrict__ tau_mem,
    float* __restrict__ out) {
  __shared__ float s_end[CHUNKS * NCOL];
  __shared__ float s_carry[CHUNKS * NCOL];

  const int tid = threadIdx.x;
  const int c = tid >> 5;          // chunk index 0..31
  const int l = tid & 31;          // n-lane 0..31 (consecutive n -> coalesced)
  const int b = blockIdx.x >> 7;   // batch 0..15   (N/NCOL = 128 groups)
  const int ng = blockIdx.x & 127; // n-group 0..127

  const float tau = tau_mem[0];
  const float alpha = expf(-1.0f / tau);
  const float aL = expf(-(float)CLEN / tau);  // alpha^CLEN exactly

  const unsigned base = ((unsigned)(b * T) + (unsigned)(c * CLEN)) * (unsigned)N
                        + (unsigned)(ng * NCOL + l);

  // Load chunk (32 independent coalesced loads, stride N between t steps)
  float v[CLEN];
#pragma unroll
  for (int j = 0; j < CLEN; ++j) v[j] = in[base + (unsigned)j * N];

  // Local scan with zero initial state
  float s = 0.0f;
#pragma unroll
  for (int j = 0; j < CLEN; ++j) {
    s = fmaf(alpha, s, v[j]);
    v[j] = s;
  }
  s_end[c * NCOL + l] = s;
  __syncthreads();

  // First NCOL threads: serial carry combine across the 32 chunks (per n-lane)
  if (tid < NCOL) {
    float S = 0.0f;
#pragma unroll
    for (int cc = 0; cc < CHUNKS; ++cc) {
      s_carry[cc * NCOL + tid] = S;            // carry INTO chunk cc
      S = fmaf(aL, S, s_end[cc * NCOL + tid]); // state at end of chunk cc
    }
  }
  __syncthreads();

  // Fix up with incoming carry and store: out = v[j] + alpha^(j+1)*carry
  const float carry = s_carry[c * NCOL + l];
  float f = alpha;
#pragma unroll
  for (int j = 0; j < CLEN; ++j) {
    out[base + (unsigned)j * N] = fmaf(f, carry, v[j]);
    f *= alpha;
  }
}

extern "C" void kernel_launch(void* const* d_in, const int* in_sizes, int n_in,
                              void* d_out, int out_size, void* d_ws, size_t ws_size,
                              hipStream_t stream) {
  const float* in = (const float*)d_in[0];
  const float* tau = (const float*)d_in[1];
  float* out = (float*)d_out;
  const int grid = B * (N / NCOL);  // 16 * 128 = 2048 blocks
  expleak_kernel<<<grid, CHUNKS * NCOL, 0, stream>>>(in, tau, out);
}